// Round 3
// baseline (33715.805 us; speedup 1.0000x reference)
//
#include <hip/hip_runtime.h>
#include <hip/hip_bf16.h>
#include <hip/hip_cooperative_groups.h>

// GRU: T=512, B=64, H=1024, L=2, gate order r|z|n (PyTorch).
// Round 3: fp16 compute (round-2 numerics: absmax 0.0078 << 0.058) + PING-PONG
// h buffers. Round 2 had a true race: between consecutive grid.sync()s, WGs
// read h-state t and wrote h-state t+1 to the SAME buffer; eager launch ran
// lockstep and passed, graph replay perturbed timing and failed re-validation.
// Ping-pong (read buf[t&1], write buf[(t+1)&1]) is race-free with one barrier
// per step: writes to buf[t&1] in iter t+1 happen only after sync(t), which
// is after all iter-t reads of buf[t&1] completed.
//
// Structure: per layer ONE cooperative kernel, 256 WGs x 256 thr (1 WG/CU).
// WG = (batch group q: 16 rows, unit block u: 16 units). Wave = K-quarter of
// both GEMMs; 48 weight rows resident in VGPRs (192 VGPRs/lane) all 512 steps.
// Per step: 48 MFMAs (16x16x32 f16) -> LDS reduce over 4 waves -> gate
// epilogue -> write h (f16, ping-pong global) -> grid.sync().

#define TT 512
#define BB 64
#define HH 1024

typedef short f16x8 __attribute__((ext_vector_type(8)));
typedef float f32x4 __attribute__((ext_vector_type(4)));

#define MFMA16(a, b, c) __builtin_amdgcn_mfma_f32_16x16x32_f16(a, b, c, 0, 0, 0)

__device__ __forceinline__ unsigned short f2h(float f) {
    _Float16 h = (_Float16)f;   // RNE
    return *(unsigned short*)&h;
}

__global__ void cvt_f32_f16_x4(const float4* __restrict__ src,
                               ushort4* __restrict__ dst, int n4) {
    int i = blockIdx.x * blockDim.x + threadIdx.x;
    if (i >= n4) return;
    float4 v = src[i];
    ushort4 o;
    o.x = f2h(v.x); o.y = f2h(v.y); o.z = f2h(v.z); o.w = f2h(v.w);
    dst[i] = o;
}

__global__ __launch_bounds__(256, 1) void gru_layer_k(
    const unsigned short* __restrict__ Wih,   // [3072][1024] f16 (layer slice)
    const unsigned short* __restrict__ Whh,   // [3072][1024] f16
    const float* __restrict__ bih,            // [3072]
    const float* __restrict__ bhh,            // [3072]
    const float* __restrict__ h0,             // [64][1024] fp32 (layer slice)
    const unsigned short* __restrict__ xin,   // [512][64][1024] f16
    unsigned short* hbuf0,                    // [64][1024] f16, pre-init to h0
    unsigned short* hbuf1,                    // [64][1024] f16 ping-pong
    unsigned short* ybf,                      // f16 y out (layer 1)
    float* yf32,                              // fp32 y out (layer 2 -> d_out)
    float* hn_out,                            // [64][1024] fp32 final h
    int out_f32)
{
    const int tid  = threadIdx.x;
    const int wg   = blockIdx.x;
    const int q    = wg >> 6;    // batch group: rows [16q, 16q+16)
    const int u    = wg & 63;    // unit block: units [16u, 16u+16)
    const int wv   = tid >> 6;   // wave = K quarter
    const int lane = tid & 63;
    const int nm   = lane & 15;
    const int quad = lane >> 4;

    __shared__ float part[4][4][16][16];  // [wave][tile: r,z,nh,nx][b][j]
    __shared__ float hst[16][16];         // fp32 h state for this WG
    __shared__ float cb[4][16];           // br, bz, bn_i, bn_h

    if (tid < 16) {
        int jg = u * 16 + tid;
        cb[0][tid] = bih[jg] + bhh[jg];
        cb[1][tid] = bih[1024 + jg] + bhh[1024 + jg];
        cb[2][tid] = bih[2048 + jg];
        cb[3][tid] = bhh[2048 + jg];
    }
    {
        int bl = tid >> 4, jl = tid & 15;
        hst[bl][jl] = h0[(size_t)(q * 16 + bl) * HH + u * 16 + jl];
    }

    const int kbase = wv * 256 + quad * 8;

    // Resident weight fragments: 48 x f16x8 = 192 VGPRs/lane.
    f16x8 brh[8], bzh[8], bnh[8], brx[8], bzx[8], bnx[8];
    {
        const unsigned short* wr = Whh + (size_t)(u * 16 + nm) * HH + kbase;
        const unsigned short* wz = wr + (size_t)1024 * HH;
        const unsigned short* wn = wz + (size_t)1024 * HH;
        const unsigned short* vr = Wih + (size_t)(u * 16 + nm) * HH + kbase;
        const unsigned short* vz = vr + (size_t)1024 * HH;
        const unsigned short* vn = vz + (size_t)1024 * HH;
#pragma unroll
        for (int kk = 0; kk < 8; ++kk) {
            brh[kk] = *(const f16x8*)(wr + kk * 32);
            bzh[kk] = *(const f16x8*)(wz + kk * 32);
            bnh[kk] = *(const f16x8*)(wn + kk * 32);
            brx[kk] = *(const f16x8*)(vr + kk * 32);
            bzx[kk] = *(const f16x8*)(vz + kk * 32);
            bnx[kk] = *(const f16x8*)(vn + kk * 32);
        }
    }
    __syncthreads();

    cooperative_groups::grid_group grid = cooperative_groups::this_grid();

    const size_t hoff = (size_t)(q * 16 + nm) * HH + kbase;
    const int bl = tid >> 4, jl = tid & 15;
    const int bg = q * 16 + bl, jg = u * 16 + jl;
    const size_t hwid = (size_t)bg * HH + jg;

    for (int t = 0; t < TT; ++t) {
        const unsigned short* hrow = ((t & 1) ? hbuf1 : hbuf0) + hoff;
        unsigned short* hwr = (t & 1) ? hbuf0 : hbuf1;
        const unsigned short* xrow =
            xin + ((size_t)t * BB + q * 16 + nm) * HH + kbase;
        f32x4 ar  = {0.f, 0.f, 0.f, 0.f};
        f32x4 az  = {0.f, 0.f, 0.f, 0.f};
        f32x4 anh = {0.f, 0.f, 0.f, 0.f};
        f32x4 anx = {0.f, 0.f, 0.f, 0.f};
#pragma unroll
        for (int kk = 0; kk < 8; ++kk) {
            f16x8 ah = *(const f16x8*)(hrow + kk * 32);
            f16x8 ax = *(const f16x8*)(xrow + kk * 32);
            ar  = MFMA16(ah, brh[kk], ar);
            az  = MFMA16(ah, bzh[kk], az);
            anh = MFMA16(ah, bnh[kk], anh);
            ar  = MFMA16(ax, brx[kk], ar);
            az  = MFMA16(ax, bzx[kk], az);
            anx = MFMA16(ax, bnx[kk], anx);
        }
        // C/D layout (m89-verified, dtype-independent): row(b)=quad*4+r, col(j)=lane&15.
#pragma unroll
        for (int r = 0; r < 4; ++r) {
            part[wv][0][quad * 4 + r][nm] = ar[r];
            part[wv][1][quad * 4 + r][nm] = az[r];
            part[wv][2][quad * 4 + r][nm] = anh[r];
            part[wv][3][quad * 4 + r][nm] = anx[r];
        }
        __syncthreads();

        float sr  = part[0][0][bl][jl] + part[1][0][bl][jl]
                  + part[2][0][bl][jl] + part[3][0][bl][jl];
        float sz  = part[0][1][bl][jl] + part[1][1][bl][jl]
                  + part[2][1][bl][jl] + part[3][1][bl][jl];
        float snh = part[0][2][bl][jl] + part[1][2][bl][jl]
                  + part[2][2][bl][jl] + part[3][2][bl][jl];
        float snx = part[0][3][bl][jl] + part[1][3][bl][jl]
                  + part[2][3][bl][jl] + part[3][3][bl][jl];

        float rg = 1.f / (1.f + __expf(-(sr + cb[0][jl])));
        float zg = 1.f / (1.f + __expf(-(sz + cb[1][jl])));
        float na = snx + cb[2][jl] + rg * (snh + cb[3][jl]);
        float ng = 1.f - 2.f / (1.f + __expf(2.f * na));  // tanh, overflow-safe
        float hp = hst[bl][jl];
        float hnv = (1.f - zg) * ng + zg * hp;
        hst[bl][jl] = hnv;

        unsigned short hb = f2h(hnv);
        hwr[hwid] = hb;
        size_t yi = ((size_t)t * BB + bg) * HH + jg;
        if (out_f32) yf32[yi] = hnv;
        else         ybf[yi] = hb;
        if (t == TT - 1) hn_out[hwid] = hnv;

        grid.sync();   // release state t+1 (includes block sync + device fences)
    }
}

extern "C" void kernel_launch(void* const* d_in, const int* in_sizes, int n_in,
                              void* d_out, int out_size, void* d_ws, size_t ws_size,
                              hipStream_t stream) {
    const float* x   = (const float*)d_in[0];   // [512,64,1024]
    const float* h0  = (const float*)d_in[1];   // [2,64,1024]
    const float* Wih = (const float*)d_in[2];   // [2,3072,1024]
    const float* Whh = (const float*)d_in[3];   // [2,3072,1024]
    const float* bih = (const float*)d_in[4];   // [2,3072]
    const float* bhh = (const float*)d_in[5];   // [2,3072]
    float* out = (float*)d_out;                 // out [512,64,1024] ++ h_n [2,64,1024]

    char* ws = (char*)d_ws;
    unsigned short* x_f16  = (unsigned short*)(ws);               // 67,108,864 B
    unsigned short* ys1    = (unsigned short*)(ws + 67108864);    // 67,108,864 B
    unsigned short* Wih_h  = (unsigned short*)(ws + 134217728);   // 12,582,912 B
    unsigned short* Whh_h  = (unsigned short*)(ws + 146800640);   // 12,582,912 B
    unsigned short* hbuf0  = (unsigned short*)(ws + 159383552);   // 131,072 B
    unsigned short* hbuf1  = (unsigned short*)(ws + 159514624);   // 131,072 B

    cvt_f32_f16_x4<<<32768, 256, 0, stream>>>((const float4*)x,   (ushort4*)x_f16, 8388608);
    cvt_f32_f16_x4<<<6144,  256, 0, stream>>>((const float4*)Wih, (ushort4*)Wih_h, 1572864);
    cvt_f32_f16_x4<<<6144,  256, 0, stream>>>((const float4*)Whh, (ushort4*)Whh_h, 1572864);
    cvt_f32_f16_x4<<<64,    256, 0, stream>>>((const float4*)h0,  (ushort4*)hbuf0, 16384);

    float* hn_base = out + (size_t)TT * BB * HH;   // 33,554,432

    {   // layer 0: x_f16 -> ys1 (f16), h_n[0]
        const unsigned short* a0 = Wih_h;
        const unsigned short* a1 = Whh_h;
        const float* a2 = bih;
        const float* a3 = bhh;
        const float* a4 = h0;
        const unsigned short* a5 = x_f16;
        unsigned short* a6 = hbuf0;
        unsigned short* a7 = hbuf1;
        unsigned short* a8 = ys1;
        float* a9 = out;        // unused (out_f32 = 0)
        float* a10 = hn_base;
        int a11 = 0;
        void* args[] = {&a0, &a1, &a2, &a3, &a4, &a5, &a6, &a7, &a8, &a9, &a10, &a11};
        hipLaunchCooperativeKernel((void*)gru_layer_k, dim3(256), dim3(256),
                                   args, 0, stream);
    }

    cvt_f32_f16_x4<<<64, 256, 0, stream>>>((const float4*)(h0 + 65536),
                                           (ushort4*)hbuf0, 16384);

    {   // layer 1: ys1 -> d_out (fp32), h_n[1]
        const unsigned short* a0 = Wih_h + 3145728;
        const unsigned short* a1 = Whh_h + 3145728;
        const float* a2 = bih + 3072;
        const float* a3 = bhh + 3072;
        const float* a4 = h0 + 65536;
        const unsigned short* a5 = ys1;
        unsigned short* a6 = hbuf0;
        unsigned short* a7 = hbuf1;
        unsigned short* a8 = ys1;   // unused (out_f32 = 1)
        float* a9 = out;
        float* a10 = hn_base + 65536;
        int a11 = 1;
        void* args[] = {&a0, &a1, &a2, &a3, &a4, &a5, &a6, &a7, &a8, &a9, &a10, &a11};
        hipLaunchCooperativeKernel((void*)gru_layer_k, dim3(256), dim3(256),
                                   args, 0, stream);
    }
}